// Round 7
// baseline (9249.718 us; speedup 1.0000x reference)
//
#include <hip/hip_runtime.h>

// Fused persistent DOPRI5 — round-6 numerics, LDS shrunk to 80 KiB for
// 2 blocks/CU (8 waves/CU, 2 waves/SIMD, grid 512 fully resident, 1 pass).
// Unpadded [row][128] bf16 LDS with chunk-XOR swizzle:
//   ushort idx = row*128 + (((k>>3) ^ (row&7))<<3) + (k&7)
// Every b128 access is one 16B chunk; write and read sides share the same
// mapping (plain C++ both sides -> consistent by construction).
// State: y fp32 + k1 fp32 + k2..k5 packed-bf16 deltas vs k1 (~205 VGPR).
// 4-wave WG -> 256 arch VGPRs (round-6-proven). No inline asm.

#define DT 0.01f
#define N_STEPS 100

typedef __attribute__((ext_vector_type(8))) short short8;
typedef __attribute__((ext_vector_type(4))) float f32x4;

// DT-premultiplied DOPRI5 tableau
#define A21 (DT * 0.2f)
#define A31 (DT * 3.0f / 40.0f)
#define A32 (DT * 9.0f / 40.0f)
#define A41 (DT * 44.0f / 45.0f)
#define A42 (-DT * 56.0f / 15.0f)
#define A43 (DT * 32.0f / 9.0f)
#define A51 (DT * 19372.0f / 6561.0f)
#define A52 (-DT * 25360.0f / 2187.0f)
#define A53 (DT * 64448.0f / 6561.0f)
#define A54 (-DT * 212.0f / 729.0f)
#define A61 (DT * 9017.0f / 3168.0f)
#define A62 (-DT * 355.0f / 33.0f)
#define A63 (DT * 46732.0f / 5247.0f)
#define A64 (DT * 49.0f / 176.0f)
#define A65 (-DT * 5103.0f / 18656.0f)
#define B1 (DT * 35.0f / 384.0f)
#define B3 (DT * 500.0f / 1113.0f)
#define B4 (DT * 125.0f / 192.0f)
#define B5 (-DT * 2187.0f / 6784.0f)
#define B6 (DT * 11.0f / 84.0f)

// delta form: z_i = y + (sum_j a_ij)*k1 + sum_{j>=2} a_ij*(k_j - k1)
#define C2_1 (A21)
#define C3_1 (A31 + A32)
#define C4_1 (A41 + A42 + A43)
#define C5_1 (A51 + A52 + A53 + A54)
#define C6_1 (A61 + A62 + A63 + A64 + A65)
#define CY_1 (B1 + B3 + B4 + B5)

__device__ __forceinline__ unsigned short f2bf(float f) {
  unsigned u = __builtin_bit_cast(unsigned, f);
  u += 0x7fffu + ((u >> 16) & 1u);  // round-to-nearest-even
  return (unsigned short)(u >> 16);
}

__device__ __forceinline__ float bflo(unsigned d) {
  return __builtin_bit_cast(float, d << 16);
}
__device__ __forceinline__ float bfhi(unsigned d) {
  return __builtin_bit_cast(float, d & 0xffff0000u);
}

__device__ __forceinline__ float fast_tanh(float x) {
  float xc = fminf(fmaxf(x, -9.f), 9.f);
  float e = __expf(2.f * xc);
  return 1.f - 2.f * __builtin_amdgcn_rcpf(e + 1.f);
}

// swizzled ushort index into an unpadded [row][128] bf16 tile
__device__ __forceinline__ int widx(int row, int k) {
  return row * 128 + ((((k >> 3) ^ (row & 7)) << 3) | (k & 7));
}

// One f(z) evaluation for this wave's 16-row tile.
// zfun(slot)->float; kfun(nt, f32x4) consumes k=f(z) (bias2 included).
template <typename ZF, typename KF>
__device__ __forceinline__ void feval(unsigned short* zb,
                                      const unsigned short* w1t,
                                      const unsigned short* w2t,
                                      const float (&bias1)[8],
                                      const float (&bias2)[8], int kg, int ln,
                                      ZF zfun, KF kfun) {
  // ---- write z (bf16) to bounce buffer (swizzled [16][128]) ----
#pragma unroll
  for (int nt = 0; nt < 8; nt++)
#pragma unroll
    for (int r = 0; r < 4; r++)
      zb[widx(4 * kg + r, nt * 16 + ln)] = f2bf(zfun(nt * 4 + r));

  // ---- read A fragments: lane holds A[row=ln][k = ks*32 + kg*8 + j] ----
  short8 af[4];
#pragma unroll
  for (int ks = 0; ks < 4; ks++)
    af[ks] = *(const short8*)&zb[widx(ln, ks * 32 + kg * 8)];

  // ---- GEMM1 (B = W1 from LDS) + bias + tanh, write h back ----
#pragma unroll
  for (int nt = 0; nt < 8; nt++) {
    f32x4 acc = {bias1[nt], bias1[nt], bias1[nt], bias1[nt]};
#pragma unroll
    for (int ks = 0; ks < 4; ks++) {
      short8 bfrag = *(const short8*)&w1t[widx(nt * 16 + ln, ks * 32 + kg * 8)];
      acc = __builtin_amdgcn_mfma_f32_16x16x32_bf16(af[ks], bfrag, acc, 0, 0, 0);
    }
#pragma unroll
    for (int r = 0; r < 4; r++)
      zb[widx(4 * kg + r, nt * 16 + ln)] = f2bf(fast_tanh(acc[r]));
  }

  // ---- read h A-fragments ----
  short8 ah[4];
#pragma unroll
  for (int ks = 0; ks < 4; ks++)
    ah[ks] = *(const short8*)&zb[widx(ln, ks * 32 + kg * 8)];

  // ---- GEMM2 (B = W2 from LDS) + bias -> kfun ----
#pragma unroll
  for (int nt = 0; nt < 8; nt++) {
    f32x4 acc = {bias2[nt], bias2[nt], bias2[nt], bias2[nt]};
#pragma unroll
    for (int ks = 0; ks < 4; ks++) {
      short8 bfrag = *(const short8*)&w2t[widx(nt * 16 + ln, ks * 32 + kg * 8)];
      acc = __builtin_amdgcn_mfma_f32_16x16x32_bf16(ah[ks], bfrag, acc, 0, 0, 0);
    }
    kfun(nt, acc);
  }
}

__global__ __launch_bounds__(256, 1) void ode_kernel(
    const float* __restrict__ x, const float* __restrict__ W1,
    const float* __restrict__ b1, const float* __restrict__ W2,
    const float* __restrict__ b2, float* __restrict__ out) {
  __shared__ unsigned short w1t[128 * 128];      // 32768 B: W1^T bf16, swizzled
  __shared__ unsigned short w2t[128 * 128];      // 32768 B: W2^T bf16, swizzled
  __shared__ unsigned short zb_all[4][16 * 128]; // 16384 B: per-wave bounce
  // total 81920 B = exactly half of 160 KiB -> 2 blocks/CU

  const int tid = threadIdx.x;
  const int wave = tid >> 6;
  const int lane = tid & 63;
  const int ln = lane & 15;   // MFMA col within tile / A row
  const int kg = lane >> 4;   // lane group

  // one-time: stage W1^T and W2^T into LDS as bf16 (swizzled)
  for (int i = tid; i < 128 * 128; i += 256) {
    int k = i >> 7, n = i & 127;
    w1t[widx(n, k)] = f2bf(W1[i]);
    w2t[widx(n, k)] = f2bf(W2[i]);
  }
  __syncthreads();

  float bias1[8], bias2[8];
#pragma unroll
  for (int nt = 0; nt < 8; nt++) {
    bias1[nt] = b1[nt * 16 + ln];
    bias2[nt] = b2[nt * 16 + ln];
  }

  unsigned short* zb = &zb_all[wave][0];
  const int rowbase = blockIdx.x * 64 + wave * 16;

  // State in C/D layout: slot i = nt*4 + r holds element [row=4*kg+r][col=nt*16+ln]
  // y, k1 fp32; k2..k5 as packed-bf16 deltas vs k1: kd[i-2][slot>>1]
  float y[32], k1f[32];
  unsigned kd[4][16];
#pragma unroll
  for (int nt = 0; nt < 8; nt++)
#pragma unroll
    for (int r = 0; r < 4; r++)
      y[nt * 4 + r] = x[(rowbase + 4 * kg + r) * 128 + nt * 16 + ln];

  auto dv = [&](int i, int s) -> float {  // delta k_{i+2} - k1
    unsigned d = kd[i][s >> 1];
    return (s & 1) ? bfhi(d) : bflo(d);
  };
  auto dstore = [&](int i, int nt, f32x4 a) {
    unsigned lo0 = f2bf(a[0] - k1f[nt * 4 + 0]);
    unsigned hi0 = f2bf(a[1] - k1f[nt * 4 + 1]);
    unsigned lo1 = f2bf(a[2] - k1f[nt * 4 + 2]);
    unsigned hi1 = f2bf(a[3] - k1f[nt * 4 + 3]);
    kd[i][nt * 2 + 0] = lo0 | (hi0 << 16);
    kd[i][nt * 2 + 1] = lo1 | (hi1 << 16);
  };

#pragma unroll 1
  for (int step = 0; step < N_STEPS; step++) {
    feval(zb, w1t, w2t, bias1, bias2, kg, ln,
          [&](int s) { return y[s]; },
          [&](int nt, f32x4 a) {
#pragma unroll
            for (int r = 0; r < 4; r++) k1f[nt * 4 + r] = a[r];
          });
    feval(zb, w1t, w2t, bias1, bias2, kg, ln,
          [&](int s) { return __builtin_fmaf(C2_1, k1f[s], y[s]); },
          [&](int nt, f32x4 a) { dstore(0, nt, a); });
    feval(zb, w1t, w2t, bias1, bias2, kg, ln,
          [&](int s) {
            float z = __builtin_fmaf(C3_1, k1f[s], y[s]);
            return __builtin_fmaf(A32, dv(0, s), z);
          },
          [&](int nt, f32x4 a) { dstore(1, nt, a); });
    feval(zb, w1t, w2t, bias1, bias2, kg, ln,
          [&](int s) {
            float z = __builtin_fmaf(C4_1, k1f[s], y[s]);
            z = __builtin_fmaf(A42, dv(0, s), z);
            return __builtin_fmaf(A43, dv(1, s), z);
          },
          [&](int nt, f32x4 a) { dstore(2, nt, a); });
    feval(zb, w1t, w2t, bias1, bias2, kg, ln,
          [&](int s) {
            float z = __builtin_fmaf(C5_1, k1f[s], y[s]);
            z = __builtin_fmaf(A52, dv(0, s), z);
            z = __builtin_fmaf(A53, dv(1, s), z);
            return __builtin_fmaf(A54, dv(2, s), z);
          },
          [&](int nt, f32x4 a) { dstore(3, nt, a); });
    feval(zb, w1t, w2t, bias1, bias2, kg, ln,
          [&](int s) {
            float z = __builtin_fmaf(C6_1, k1f[s], y[s]);
            z = __builtin_fmaf(A62, dv(0, s), z);
            z = __builtin_fmaf(A63, dv(1, s), z);
            z = __builtin_fmaf(A64, dv(2, s), z);
            return __builtin_fmaf(A65, dv(3, s), z);
          },
          [&](int nt, f32x4 a) {
#pragma unroll
            for (int r = 0; r < 4; r++) {
              int s = nt * 4 + r;
              float inc = CY_1 * k1f[s];
              inc = __builtin_fmaf(B3, dv(1, s), inc);
              inc = __builtin_fmaf(B4, dv(2, s), inc);
              inc = __builtin_fmaf(B5, dv(3, s), inc);
              inc = __builtin_fmaf(B6, a[r], inc);
              y[s] += inc;
            }
          });
  }

#pragma unroll
  for (int nt = 0; nt < 8; nt++)
#pragma unroll
    for (int r = 0; r < 4; r++)
      out[(rowbase + 4 * kg + r) * 128 + nt * 16 + ln] = y[nt * 4 + r];
}

extern "C" void kernel_launch(void* const* d_in, const int* in_sizes, int n_in,
                              void* d_out, int out_size, void* d_ws,
                              size_t ws_size, hipStream_t stream) {
  const float* x = (const float*)d_in[0];
  const float* W1 = (const float*)d_in[1];
  const float* b1 = (const float*)d_in[2];
  const float* W2 = (const float*)d_in[3];
  const float* b2 = (const float*)d_in[4];
  float* out = (float*)d_out;

  dim3 grid(512), block(256);
  hipLaunchKernelGGL(ode_kernel, grid, block, 0, stream, x, W1, b1, W2, b2,
                     out);
}